// Round 1
// baseline (9200.991 us; speedup 1.0000x reference)
//
#include <hip/hip_runtime.h>
#include <hip/hip_bf16.h>
#include <math.h>

#define NTOK 49
#define CDIM 192
#define NH   6
#define HD   32
#define NTHREADS 256
#define SSTR 50   // score row stride (floats)

__device__ __forceinline__ float bfu2f(unsigned int u16) {
    return __uint_as_float(u16 << 16);
}
__device__ __forceinline__ unsigned short f2bf(float f) {
    union { __hip_bfloat16 h; unsigned short u; } cv;
    cv.h = __float2bfloat16(f);
    return cv.u;
}
__device__ __forceinline__ float lo16(unsigned int v){ return bfu2f(v & 0xffffu); }
__device__ __forceinline__ float hi16(unsigned int v){ return bfu2f(v >> 16); }

__global__ __launch_bounds__(NTHREADS)
void swin_block_kernel(
    const float* __restrict__ x,   const int* __restrict__ amask,
    const float* __restrict__ g1,  const float* __restrict__ b1,
    const float* __restrict__ wqkv,const float* __restrict__ bqkv,
    const float* __restrict__ wpr, const float* __restrict__ bpr,
    const float* __restrict__ g2,  const float* __restrict__ b2,
    const float* __restrict__ wf1, const float* __restrict__ bf1,
    const float* __restrict__ wf2, const float* __restrict__ bf2v,
    float* __restrict__ out)
{
    // LDS: sxn 18816 + accs 37632 + chunk 19616 + misc ~= 76.5 KB -> 2 blocks/CU
    __shared__ unsigned short sxn[NTOK*CDIM];            // bf16 bits: xn (LN1), later xn2 (LN2)
    __shared__ float accs[NTOK*CDIM];                    // fp32 residual accumulator (x -> x1 -> out)
    __shared__ __align__(16) unsigned char chunkraw[19616];

    unsigned short* v_s  = (unsigned short*)chunkraw;            // 49x32 bf16 (3136 B)
    unsigned short* q_s  = (unsigned short*)(chunkraw + 3136);   // 49x32 bf16
    unsigned short* k_s  = (unsigned short*)(chunkraw + 6272);   // 49x32 bf16
    float*          s_s  = (float*)(chunkraw + 9408);            // 49x50 f32 scores/probs
    float*          oh_s = (float*)(chunkraw + 3136);            // 49x32 f32, aliases q_s+k_s (dead then)
    unsigned short* hm_s = (unsigned short*)chunkraw;            // 49x192 bf16 (MLP phase)

    const int b    = blockIdx.x;
    const int tid  = threadIdx.x;
    const int lane = tid & 63;
    const int wid  = tid >> 6;
    const int j32  = tid & 31;
    const int rg   = tid >> 5;   // 0..7
    const float* xb = x + (size_t)b * (NTOK*CDIM);

    // ---------------- LN1 + residual init (accs = x + b_proj) ----------------
    for (int i = wid; i < NTOK; i += 4) {
        float v0 = xb[i*CDIM + lane];
        float v1 = xb[i*CDIM + lane + 64];
        float v2 = xb[i*CDIM + lane + 128];
        float s  = v0 + v1 + v2;
        float s2 = v0*v0 + v1*v1 + v2*v2;
        #pragma unroll
        for (int off = 32; off > 0; off >>= 1) {
            s  += __shfl_xor(s,  off, 64);
            s2 += __shfl_xor(s2, off, 64);
        }
        float m  = s  * (1.0f/CDIM);
        float vr = s2 * (1.0f/CDIM) - m*m;
        float rs = rsqrtf(vr + 1e-5f);
        sxn[i*CDIM + lane]       = f2bf((v0-m)*rs*g1[lane]     + b1[lane]);
        sxn[i*CDIM + lane + 64]  = f2bf((v1-m)*rs*g1[lane+64]  + b1[lane+64]);
        sxn[i*CDIM + lane + 128] = f2bf((v2-m)*rs*g1[lane+128] + b1[lane+128]);
        accs[i*CDIM + lane]       = v0 + bpr[lane];
        accs[i*CDIM + lane + 64]  = v1 + bpr[lane+64];
        accs[i*CDIM + lane + 128] = v2 + bpr[lane+128];
    }
    __syncthreads();

    // ---------------- attention, one head at a time ----------------
    const float scale = 0.17677669529663687f; // 32^-0.5
    for (int h = 0; h < NH; ++h) {
        // qkv GEMM for head h: thread = (col j32, rowgroup rg); 7 rows x 3 mats accum
        {
            float aq[7], ak[7], av[7];
            #pragma unroll
            for (int t = 0; t < 7; ++t) { aq[t]=0.f; ak[t]=0.f; av[t]=0.f; }
            const float* wq = wqkv + (size_t)(h*HD + j32) * CDIM;
            const float* wk = wq + (size_t)CDIM * CDIM;
            const float* wv = wk + (size_t)CDIM * CDIM;
            for (int k0 = 0; k0 < CDIM; k0 += 4) {
                const float4 wq4 = *(const float4*)(wq + k0);
                const float4 wk4 = *(const float4*)(wk + k0);
                const float4 wv4 = *(const float4*)(wv + k0);
                #pragma unroll
                for (int t = 0; t < 7; ++t) {
                    int i = rg + t*8; if (i > 48) i = 48;
                    uint2 a4 = *(const uint2*)(sxn + i*CDIM + k0);
                    float a0 = lo16(a4.x), a1 = hi16(a4.x);
                    float a2 = lo16(a4.y), a3 = hi16(a4.y);
                    aq[t] = fmaf(a0, wq4.x, aq[t]); aq[t] = fmaf(a1, wq4.y, aq[t]);
                    aq[t] = fmaf(a2, wq4.z, aq[t]); aq[t] = fmaf(a3, wq4.w, aq[t]);
                    ak[t] = fmaf(a0, wk4.x, ak[t]); ak[t] = fmaf(a1, wk4.y, ak[t]);
                    ak[t] = fmaf(a2, wk4.z, ak[t]); ak[t] = fmaf(a3, wk4.w, ak[t]);
                    av[t] = fmaf(a0, wv4.x, av[t]); av[t] = fmaf(a1, wv4.y, av[t]);
                    av[t] = fmaf(a2, wv4.z, av[t]); av[t] = fmaf(a3, wv4.w, av[t]);
                }
            }
            float bq = bqkv[h*HD + j32];
            float bk = bqkv[CDIM + h*HD + j32];
            float bv = bqkv[2*CDIM + h*HD + j32];
            #pragma unroll
            for (int t = 0; t < 7; ++t) {
                int i = rg + t*8;
                if (i < NTOK) {
                    q_s[i*HD + j32] = f2bf((aq[t] + bq) * scale);
                    k_s[i*HD + j32] = f2bf(ak[t] + bk);
                    v_s[i*HD + j32] = f2bf(av[t] + bv);
                }
            }
        }
        __syncthreads();

        // scores = q.k^T + mask
        const int* mb = amask + (size_t)b * (NTOK*NTOK);
        for (int idx = tid; idx < NTOK*NTOK; idx += NTHREADS) {
            int i = idx / NTOK, j = idx - i*NTOK;
            const uint4* qp = (const uint4*)(q_s + i*HD);
            const uint4* kp = (const uint4*)(k_s + j*HD);
            float d = 0.f;
            #pragma unroll
            for (int t = 0; t < 4; ++t) {
                uint4 qa = qp[t], kb = kp[t];
                d = fmaf(lo16(qa.x), lo16(kb.x), d); d = fmaf(hi16(qa.x), hi16(kb.x), d);
                d = fmaf(lo16(qa.y), lo16(kb.y), d); d = fmaf(hi16(qa.y), hi16(kb.y), d);
                d = fmaf(lo16(qa.z), lo16(kb.z), d); d = fmaf(hi16(qa.z), hi16(kb.z), d);
                d = fmaf(lo16(qa.w), lo16(kb.w), d); d = fmaf(hi16(qa.w), hi16(kb.w), d);
            }
            s_s[i*SSTR + j] = (mb[idx] == 0) ? -INFINITY : d;
        }
        __syncthreads();

        // row softmax (one row per wave-iteration; lanes 0..48 hold the row)
        for (int i = wid; i < NTOK; i += 4) {
            float sv = (lane < NTOK) ? s_s[i*SSTR + lane] : -INFINITY;
            float mx = sv;
            #pragma unroll
            for (int off = 32; off > 0; off >>= 1) mx = fmaxf(mx, __shfl_xor(mx, off, 64));
            float e = (lane < NTOK) ? __expf(sv - mx) : 0.f;
            float se = e;
            #pragma unroll
            for (int off = 32; off > 0; off >>= 1) se += __shfl_xor(se, off, 64);
            if (lane < NTOK) s_s[i*SSTR + lane] = e / se;
        }
        __syncthreads();

        // o_h = P @ V  (49x32), into oh_s (aliases dead q_s/k_s)
        for (int idx = tid; idx < NTOK*HD; idx += NTHREADS) {
            int i = idx >> 5, d2 = idx & 31;
            const float* pr = s_s + i*SSTR;
            float o = 0.f;
            #pragma unroll 7
            for (int j = 0; j < NTOK; ++j)
                o = fmaf(pr[j], bfu2f(v_s[j*HD + d2]), o);
            oh_s[idx] = o;
        }
        __syncthreads();

        // proj accumulate: accs[i][c] += sum_d oh[i][d] * w_proj[c][h*32+d]
        for (int idx = tid; idx < NTOK*CDIM; idx += NTHREADS) {
            int i = idx / CDIM, c = idx - i*CDIM;
            const float* wp = wpr + (size_t)c*CDIM + h*HD;
            const float* op = oh_s + i*HD;
            float o = 0.f;
            #pragma unroll
            for (int d0 = 0; d0 < HD; d0 += 4) {
                float4 w4 = *(const float4*)(wp + d0);
                o = fmaf(op[d0],   w4.x, o);
                o = fmaf(op[d0+1], w4.y, o);
                o = fmaf(op[d0+2], w4.z, o);
                o = fmaf(op[d0+3], w4.w, o);
            }
            accs[idx] += o;
        }
        __syncthreads();
    } // heads

    // ---------------- LN2 (accs holds x1) ----------------
    for (int i = wid; i < NTOK; i += 4) {
        float v0 = accs[i*CDIM + lane];
        float v1 = accs[i*CDIM + lane + 64];
        float v2 = accs[i*CDIM + lane + 128];
        float s  = v0 + v1 + v2;
        float s2 = v0*v0 + v1*v1 + v2*v2;
        #pragma unroll
        for (int off = 32; off > 0; off >>= 1) {
            s  += __shfl_xor(s,  off, 64);
            s2 += __shfl_xor(s2, off, 64);
        }
        float m  = s  * (1.0f/CDIM);
        float vr = s2 * (1.0f/CDIM) - m*m;
        float rs = rsqrtf(vr + 1e-5f);
        sxn[i*CDIM + lane]       = f2bf((v0-m)*rs*g2[lane]     + b2[lane]);
        sxn[i*CDIM + lane + 64]  = f2bf((v1-m)*rs*g2[lane+64]  + b2[lane+64]);
        sxn[i*CDIM + lane + 128] = f2bf((v2-m)*rs*g2[lane+128] + b2[lane+128]);
    }
    __syncthreads();

    // ---------------- MLP in 4 hidden chunks of 192 ----------------
    for (int jc = 0; jc < 4; ++jc) {
        // fc1 chunk + exact gelu -> hm_s (bf16). Thread tile: 6 cols x 7 rows.
        {
            float am[6][7];
            #pragma unroll
            for (int mm = 0; mm < 6; ++mm)
                #pragma unroll
                for (int t = 0; t < 7; ++t) am[mm][t] = 0.f;
            const float* w0 = wf1 + (size_t)(jc*CDIM + j32) * CDIM;
            for (int k0 = 0; k0 < CDIM; k0 += 4) {
                float4 w4[6];
                #pragma unroll
                for (int mm = 0; mm < 6; ++mm)
                    w4[mm] = *(const float4*)(w0 + (size_t)(32*CDIM)*mm + k0);
                #pragma unroll
                for (int t = 0; t < 7; ++t) {
                    int i = rg + t*8; if (i > 48) i = 48;
                    uint2 a4 = *(const uint2*)(sxn + i*CDIM + k0);
                    float a0 = lo16(a4.x), a1 = hi16(a4.x);
                    float a2 = lo16(a4.y), a3 = hi16(a4.y);
                    #pragma unroll
                    for (int mm = 0; mm < 6; ++mm) {
                        am[mm][t] = fmaf(a0, w4[mm].x, am[mm][t]);
                        am[mm][t] = fmaf(a1, w4[mm].y, am[mm][t]);
                        am[mm][t] = fmaf(a2, w4[mm].z, am[mm][t]);
                        am[mm][t] = fmaf(a3, w4[mm].w, am[mm][t]);
                    }
                }
            }
            #pragma unroll
            for (int mm = 0; mm < 6; ++mm) {
                float bb = bf1[jc*CDIM + j32 + 32*mm];
                #pragma unroll
                for (int t = 0; t < 7; ++t) {
                    int i = rg + t*8;
                    if (i < NTOK) {
                        float a  = am[mm][t] + bb;
                        float gl = 0.5f * a * (1.0f + erff(a * 0.70710678118654752f));
                        hm_s[i*CDIM + j32 + 32*mm] = f2bf(gl);
                    }
                }
            }
        }
        __syncthreads();
        // fc2 chunk accumulate into accs
        {
            float am[6][7];
            #pragma unroll
            for (int mm = 0; mm < 6; ++mm)
                #pragma unroll
                for (int t = 0; t < 7; ++t) am[mm][t] = 0.f;
            const float* w0 = wf2 + (size_t)j32 * 768 + jc*CDIM;
            for (int k0 = 0; k0 < CDIM; k0 += 4) {
                float4 w4[6];
                #pragma unroll
                for (int mm = 0; mm < 6; ++mm)
                    w4[mm] = *(const float4*)(w0 + (size_t)(32*768)*mm + k0);
                #pragma unroll
                for (int t = 0; t < 7; ++t) {
                    int i = rg + t*8; if (i > 48) i = 48;
                    uint2 a4 = *(const uint2*)(hm_s + i*CDIM + k0);
                    float a0 = lo16(a4.x), a1 = hi16(a4.x);
                    float a2 = lo16(a4.y), a3 = hi16(a4.y);
                    #pragma unroll
                    for (int mm = 0; mm < 6; ++mm) {
                        am[mm][t] = fmaf(a0, w4[mm].x, am[mm][t]);
                        am[mm][t] = fmaf(a1, w4[mm].y, am[mm][t]);
                        am[mm][t] = fmaf(a2, w4[mm].z, am[mm][t]);
                        am[mm][t] = fmaf(a3, w4[mm].w, am[mm][t]);
                    }
                }
            }
            #pragma unroll
            for (int mm = 0; mm < 6; ++mm) {
                #pragma unroll
                for (int t = 0; t < 7; ++t) {
                    int i = rg + t*8;
                    if (i < NTOK) accs[i*CDIM + j32 + 32*mm] += am[mm][t];
                }
            }
        }
        __syncthreads();
    }

    // ---------------- store out = accs + b_fc2 ----------------
    float* ob = out + (size_t)b * (NTOK*CDIM);
    for (int idx = tid; idx < NTOK*CDIM; idx += NTHREADS) {
        int c = idx - (idx / CDIM) * CDIM;
        ob[idx] = accs[idx] + bf2v[c];
    }
}

extern "C" void kernel_launch(void* const* d_in, const int* in_sizes, int n_in,
                              void* d_out, int out_size, void* d_ws, size_t ws_size,
                              hipStream_t stream) {
    (void)in_sizes; (void)n_in; (void)out_size; (void)d_ws; (void)ws_size;
    const float* x    = (const float*)d_in[0];
    const int*   am   = (const int*)d_in[1];
    const float* g1   = (const float*)d_in[2];
    const float* b1   = (const float*)d_in[3];
    const float* wqkv = (const float*)d_in[4];
    const float* bqkv = (const float*)d_in[5];
    const float* wpr  = (const float*)d_in[6];
    const float* bpr  = (const float*)d_in[7];
    const float* g2   = (const float*)d_in[8];
    const float* b2   = (const float*)d_in[9];
    const float* wf1  = (const float*)d_in[10];
    const float* bf1  = (const float*)d_in[11];
    const float* wf2  = (const float*)d_in[12];
    const float* bf2v = (const float*)d_in[13];
    swin_block_kernel<<<4096, NTHREADS, 0, stream>>>(
        x, am, g1, b1, wqkv, bqkv, wpr, bpr, g2, b2, wf1, bf1, wf2, bf2v,
        (float*)d_out);
}

// Round 2
// 2104.817 us; speedup vs baseline: 4.3714x; 4.3714x over previous
//
#include <hip/hip_runtime.h>
#include <hip/hip_bf16.h>
#include <math.h>

#define NTOK 49
#define CDIM 192
#define NH   6
#define HD   32
#define XSTR 200   // bf16 row stride for xn / oh / aproj (64-row tiles)
#define QSTR 40    // q/k per-head row stride
#define VSTR 72    // vt row stride (32 rows x 64 tokens padded)
#define PSTR 72    // p row stride

typedef short bf16x8 __attribute__((ext_vector_type(8)));
typedef float f32x4  __attribute__((ext_vector_type(4)));

__device__ __forceinline__ float bfu2f(unsigned short u) {
    return __uint_as_float(((unsigned int)u) << 16);
}
__device__ __forceinline__ short f2bf(float f) {
    union { __hip_bfloat16 h; short s; } cv; cv.h = __float2bfloat16(f); return cv.s;
}

// ---------------- weight fp32 -> bf16 prep (runs every launch; d_ws re-poisoned) ----
// segments (elems): wqkv 110592 | wproj 36864 | wf1 147456 | wf2 147456  = 442368
__global__ void conv_weights(const float* __restrict__ wqkv, const float* __restrict__ wpr,
                             const float* __restrict__ wf1,  const float* __restrict__ wf2,
                             unsigned short* __restrict__ ws) {
    int i = blockIdx.x * 256 + threadIdx.x;   // vec4 index, grid covers 110592 exactly
    int e = i * 4;
    const float* src;
    if      (e < 110592) src = wqkv + e;
    else if (e < 147456) src = wpr + (e - 110592);
    else if (e < 294912) src = wf1 + (e - 147456);
    else                 src = wf2 + (e - 294912);
    float4 v = *(const float4*)src;
    ushort4 o;
    o.x = (unsigned short)f2bf(v.x); o.y = (unsigned short)f2bf(v.y);
    o.z = (unsigned short)f2bf(v.z); o.w = (unsigned short)f2bf(v.w);
    *(ushort4*)(ws + e) = o;
}

// ---------------- fused swin block, MFMA everywhere -------------------------------
__global__ __launch_bounds__(256, 2)
void swin_mfma_kernel(const float* __restrict__ x, const int* __restrict__ amask,
                      const float* __restrict__ g1, const float* __restrict__ b1,
                      const float* __restrict__ bqkv, const float* __restrict__ bpr,
                      const float* __restrict__ g2, const float* __restrict__ b2,
                      const float* __restrict__ bf1, const float* __restrict__ bf2,
                      const unsigned short* __restrict__ wbf,
                      float* __restrict__ out)
{
    __shared__ short xn_s[64 * XSTR];                 // 25600 B: xn1 then xn2
    __shared__ short oh_s[64 * XSTR];                 // 25600 B: attn O, then hm chunk
    __shared__ __align__(16) short scr[12032];        // 24064 B: q|k|vt|p  ∪  aproj
    __shared__ unsigned long long smask_s[64];        // 512 B

    short* q_s  = scr;                    // 64x40  (5120 B)
    short* k_s  = scr + 2560;             // 64x40  (5120 B)
    short* vt_s = scr + 5120;             // 32x72  (4608 B)
    short* p_s  = scr + 7424;             // 64x72  (9216 B)
    short* ap_s = scr;                    // 49x200 bf16 (19600 B), lives after attention

    const int b    = blockIdx.x;
    const int tid  = threadIdx.x;
    const int lane = tid & 63;
    const int w    = tid >> 6;            // wave id = row-tile id
    const int l15  = lane & 15;
    const int quad = lane >> 4;
    const int rbase = 16 * w;
    const int arow  = rbase + l15;        // A-fragment row for this lane
    const float* xb = x + (size_t)b * (NTOK * CDIM);

    const unsigned short* wq_bf = wbf;            // 576x192
    const unsigned short* wp_bf = wbf + 110592;   // 192x192
    const unsigned short* w1_bf = wbf + 147456;   // 768x192
    const unsigned short* w2_bf = wbf + 294912;   // 192x768

    // ---- mask bitmap (one u64 per row; bits >=49 zero; rows 49..63 zero) ----
    if (tid < 64) {
        unsigned long long m = 0ull;
        if (tid < NTOK) {
            const int* mr = amask + (size_t)b * (NTOK * NTOK) + tid * NTOK;
            for (int j = 0; j < NTOK; ++j)
                m |= (unsigned long long)(mr[j] != 0) << j;
        }
        smask_s[tid] = m;
    }
    // ---- zero vt padding tokens 49..63 (k-dim: must not be NaN garbage) ----
    for (int idx = tid; idx < 32 * 15; idx += 256) {
        int d = idx / 15, t = 49 + (idx - d * 15);
        vt_s[d * VSTR + t] = 0;
    }
    // ---- LN1 (striped rows) ----
    for (int i = w; i < NTOK; i += 4) {
        float v0 = xb[i*CDIM + lane], v1 = xb[i*CDIM + lane + 64], v2 = xb[i*CDIM + lane + 128];
        float s = v0 + v1 + v2, s2 = v0*v0 + v1*v1 + v2*v2;
        #pragma unroll
        for (int off = 32; off > 0; off >>= 1) {
            s += __shfl_xor(s, off, 64); s2 += __shfl_xor(s2, off, 64);
        }
        float m = s * (1.0f/CDIM), vr = s2 * (1.0f/CDIM) - m*m, rs = rsqrtf(vr + 1e-5f);
        xn_s[i*XSTR + lane]       = f2bf((v0-m)*rs*g1[lane]     + b1[lane]);
        xn_s[i*XSTR + lane + 64]  = f2bf((v1-m)*rs*g1[lane+64]  + b1[lane+64]);
        xn_s[i*XSTR + lane + 128] = f2bf((v2-m)*rs*g1[lane+128] + b1[lane+128]);
    }
    __syncthreads();

    // ---- A-fragments of xn (reused across all heads) ----
    bf16x8 axn[6];
    #pragma unroll
    for (int ks = 0; ks < 6; ++ks)
        axn[ks] = *(const bf16x8*)&xn_s[arow*XSTR + ks*32 + quad*8];

    // ================= attention, per head =================
    for (int h = 0; h < NH; ++h) {
        // ---- qkv: 6 n-tiles (q0 q1 k0 k1 v0 v1), K=192 ----
        #pragma unroll
        for (int nt = 0; nt < 6; ++nt) {
            const int mat = nt >> 1, c16 = nt & 1;
            const int colb = mat*CDIM + h*HD + c16*16;
            f32x4 acc = {0.f, 0.f, 0.f, 0.f};
            #pragma unroll
            for (int ks = 0; ks < 6; ++ks) {
                bf16x8 bw = *(const bf16x8*)&wq_bf[(size_t)(colb + l15)*CDIM + ks*32 + quad*8];
                acc = __builtin_amdgcn_mfma_f32_16x16x32_bf16(axn[ks], bw, acc, 0, 0, 0);
            }
            const float bias = bqkv[colb + l15];
            #pragma unroll
            for (int reg = 0; reg < 4; ++reg) {
                int r = rbase + quad*4 + reg;
                if (r < NTOK) {
                    float val = acc[reg] + bias;
                    int ch = c16*16 + l15;
                    if      (mat == 0) q_s[r*QSTR + ch] = f2bf(val * 0.17677669529663687f);
                    else if (mat == 1) k_s[r*QSTR + ch] = f2bf(val);
                    else               vt_s[ch*VSTR + r] = f2bf(val);
                }
            }
        }
        __syncthreads();

        // ---- scores S[i][j] = q.k  (wave w: rows 16w..16w+15, 4 col-tiles) ----
        bf16x8 aq = *(const bf16x8*)&q_s[arow*QSTR + quad*8];
        f32x4 sacc[4];
        #pragma unroll
        for (int nt = 0; nt < 4; ++nt) {
            bf16x8 bk = *(const bf16x8*)&k_s[(nt*16 + l15)*QSTR + quad*8];
            f32x4 z = {0.f, 0.f, 0.f, 0.f};
            sacc[nt] = __builtin_amdgcn_mfma_f32_16x16x32_bf16(aq, bk, z, 0, 0, 0);
        }
        // ---- softmax in registers (quad-local shuffles), write P bf16 ----
        #pragma unroll
        for (int reg = 0; reg < 4; ++reg) {
            int r = rbase + quad*4 + reg;
            unsigned long long mk = smask_s[r];
            float mx = -INFINITY;
            #pragma unroll
            for (int nt = 0; nt < 4; ++nt) {
                int j = nt*16 + l15;
                float v = ((mk >> j) & 1ull) ? sacc[nt][reg] : -INFINITY;
                mx = fmaxf(mx, v);
            }
            mx = fmaxf(mx, __shfl_xor(mx, 1, 64));
            mx = fmaxf(mx, __shfl_xor(mx, 2, 64));
            mx = fmaxf(mx, __shfl_xor(mx, 4, 64));
            mx = fmaxf(mx, __shfl_xor(mx, 8, 64));
            float e[4]; float sm = 0.f;
            #pragma unroll
            for (int nt = 0; nt < 4; ++nt) {
                int j = nt*16 + l15;
                e[nt] = ((mk >> j) & 1ull) ? __expf(sacc[nt][reg] - mx) : 0.f;
                sm += e[nt];
            }
            sm += __shfl_xor(sm, 1, 64);
            sm += __shfl_xor(sm, 2, 64);
            sm += __shfl_xor(sm, 4, 64);
            sm += __shfl_xor(sm, 8, 64);
            float inv = 1.f / sm;
            if (r < NTOK) {
                #pragma unroll
                for (int nt = 0; nt < 4; ++nt)
                    p_s[r*PSTR + nt*16 + l15] = f2bf(e[nt] * inv);
            }
        }
        // ---- O = P @ V  (k = 64 padded tokens; p zeros + vt zeros past 48) ----
        bf16x8 ap0 = *(const bf16x8*)&p_s[arow*PSTR + quad*8];
        bf16x8 ap1 = *(const bf16x8*)&p_s[arow*PSTR + 32 + quad*8];
        #pragma unroll
        for (int nt = 0; nt < 2; ++nt) {
            bf16x8 bv0 = *(const bf16x8*)&vt_s[(nt*16 + l15)*VSTR + quad*8];
            bf16x8 bv1 = *(const bf16x8*)&vt_s[(nt*16 + l15)*VSTR + 32 + quad*8];
            f32x4 oa = {0.f, 0.f, 0.f, 0.f};
            oa = __builtin_amdgcn_mfma_f32_16x16x32_bf16(ap0, bv0, oa, 0, 0, 0);
            oa = __builtin_amdgcn_mfma_f32_16x16x32_bf16(ap1, bv1, oa, 0, 0, 0);
            #pragma unroll
            for (int reg = 0; reg < 4; ++reg) {
                int r = rbase + quad*4 + reg;
                if (r < NTOK) oh_s[r*XSTR + h*HD + nt*16 + l15] = f2bf(oa[reg]);
            }
        }
        __syncthreads();
    }

    // ================= proj: aproj = O @ wproj^T + bproj (bf16) =================
    {
        bf16x8 ao[6];
        #pragma unroll
        for (int ks = 0; ks < 6; ++ks)
            ao[ks] = *(const bf16x8*)&oh_s[arow*XSTR + ks*32 + quad*8];
        #pragma unroll
        for (int nt = 0; nt < 12; ++nt) {
            f32x4 pa = {0.f, 0.f, 0.f, 0.f};
            #pragma unroll
            for (int ks = 0; ks < 6; ++ks) {
                bf16x8 bw = *(const bf16x8*)&wp_bf[(size_t)(nt*16 + l15)*CDIM + ks*32 + quad*8];
                pa = __builtin_amdgcn_mfma_f32_16x16x32_bf16(ao[ks], bw, pa, 0, 0, 0);
            }
            float bias = bpr[nt*16 + l15];
            #pragma unroll
            for (int reg = 0; reg < 4; ++reg) {
                int r = rbase + quad*4 + reg;
                if (r < NTOK) ap_s[r*XSTR + nt*16 + l15] = f2bf(pa[reg] + bias);
            }
        }
    }
    __syncthreads();

    // ================= LN2: x1 = x + aproj, normalize -> xn_s =================
    for (int i = w; i < NTOK; i += 4) {
        float v0 = xb[i*CDIM + lane]       + bfu2f((unsigned short)ap_s[i*XSTR + lane]);
        float v1 = xb[i*CDIM + lane + 64]  + bfu2f((unsigned short)ap_s[i*XSTR + lane + 64]);
        float v2 = xb[i*CDIM + lane + 128] + bfu2f((unsigned short)ap_s[i*XSTR + lane + 128]);
        float s = v0 + v1 + v2, s2 = v0*v0 + v1*v1 + v2*v2;
        #pragma unroll
        for (int off = 32; off > 0; off >>= 1) {
            s += __shfl_xor(s, off, 64); s2 += __shfl_xor(s2, off, 64);
        }
        float m = s * (1.0f/CDIM), vr = s2 * (1.0f/CDIM) - m*m, rs = rsqrtf(vr + 1e-5f);
        xn_s[i*XSTR + lane]       = f2bf((v0-m)*rs*g2[lane]     + b2[lane]);
        xn_s[i*XSTR + lane + 64]  = f2bf((v1-m)*rs*g2[lane+64]  + b2[lane+64]);
        xn_s[i*XSTR + lane + 128] = f2bf((v2-m)*rs*g2[lane+128] + b2[lane+128]);
    }
    __syncthreads();

    // ================= MLP: 4 hidden chunks of 192, fc2 acc in regs =================
    {
        bf16x8 ax[6];
        #pragma unroll
        for (int ks = 0; ks < 6; ++ks)
            ax[ks] = *(const bf16x8*)&xn_s[arow*XSTR + ks*32 + quad*8];
        f32x4 facc2[12];
        #pragma unroll
        for (int nt = 0; nt < 12; ++nt) facc2[nt] = (f32x4){0.f, 0.f, 0.f, 0.f};

        for (int jc = 0; jc < 4; ++jc) {
            // fc1 chunk + gelu -> hm (oh_s reuse; rows of this wave only)
            #pragma unroll
            for (int nt2 = 0; nt2 < 12; ++nt2) {
                f32x4 fa = {0.f, 0.f, 0.f, 0.f};
                const int hc = jc*CDIM + nt2*16 + l15;
                #pragma unroll
                for (int ks = 0; ks < 6; ++ks) {
                    bf16x8 bw = *(const bf16x8*)&w1_bf[(size_t)hc*CDIM + ks*32 + quad*8];
                    fa = __builtin_amdgcn_mfma_f32_16x16x32_bf16(ax[ks], bw, fa, 0, 0, 0);
                }
                const float bias = bf1[hc];
                #pragma unroll
                for (int reg = 0; reg < 4; ++reg) {
                    float v = fa[reg] + bias;
                    float g = 0.5f * v * (1.0f + erff(v * 0.70710678118654752f));
                    oh_s[(rbase + quad*4 + reg)*XSTR + nt2*16 + l15] = f2bf(g);
                }
            }
            // fc2 partial (K = this chunk), accumulate in regs
            bf16x8 ah[6];
            #pragma unroll
            for (int ks = 0; ks < 6; ++ks)
                ah[ks] = *(const bf16x8*)&oh_s[arow*XSTR + ks*32 + quad*8];
            #pragma unroll
            for (int nt = 0; nt < 12; ++nt) {
                #pragma unroll
                for (int ks = 0; ks < 6; ++ks) {
                    bf16x8 bw = *(const bf16x8*)&w2_bf[(size_t)(nt*16 + l15)*768 + jc*CDIM + ks*32 + quad*8];
                    facc2[nt] = __builtin_amdgcn_mfma_f32_16x16x32_bf16(ah[ks], bw, facc2[nt], 0, 0, 0);
                }
            }
        }
        // ---- final: out = x + aproj + mlp + b_fc2 ----
        float* ob = out + (size_t)b * (NTOK * CDIM);
        #pragma unroll
        for (int nt = 0; nt < 12; ++nt) {
            const int col = nt*16 + l15;
            const float bias = bf2[col];
            #pragma unroll
            for (int reg = 0; reg < 4; ++reg) {
                int r = rbase + quad*4 + reg;
                if (r < NTOK)
                    ob[r*CDIM + col] = facc2[nt][reg] + bias + xb[r*CDIM + col]
                                     + bfu2f((unsigned short)ap_s[r*XSTR + col]);
            }
        }
    }
}

extern "C" void kernel_launch(void* const* d_in, const int* in_sizes, int n_in,
                              void* d_out, int out_size, void* d_ws, size_t ws_size,
                              hipStream_t stream) {
    (void)in_sizes; (void)n_in; (void)out_size; (void)ws_size;
    const float* x    = (const float*)d_in[0];
    const int*   am   = (const int*)d_in[1];
    const float* g1   = (const float*)d_in[2];
    const float* b1   = (const float*)d_in[3];
    const float* wqkv = (const float*)d_in[4];
    const float* bqkv = (const float*)d_in[5];
    const float* wpr  = (const float*)d_in[6];
    const float* bpr  = (const float*)d_in[7];
    const float* g2   = (const float*)d_in[8];
    const float* b2   = (const float*)d_in[9];
    const float* wf1  = (const float*)d_in[10];
    const float* bf1  = (const float*)d_in[11];
    const float* wf2  = (const float*)d_in[12];
    const float* bf2  = (const float*)d_in[13];
    unsigned short* wbf = (unsigned short*)d_ws;

    conv_weights<<<432, 256, 0, stream>>>(wqkv, wpr, wf1, wf2, wbf);
    swin_mfma_kernel<<<4096, 256, 0, stream>>>(
        x, am, g1, b1, bqkv, bpr, g2, b2, bf1, bf2, wbf, (float*)d_out);
}